// Round 8
// baseline (223.568 us; speedup 1.0000x reference)
//
#include <hip/hip_runtime.h>
#include <hip/hip_bf16.h>
#include <stdint.h>

// ModulatedConv2d: N=16, IC=OC=256, H=W=64, K=3, STYLE=512. fp32 in/out.
// out = demod[n,oc] * conv2d( x * (1+s)[n,ic], weight )   (StyleGAN2 identity)
// R12: modulation moved from x to weight: conv(x*s, w) = conv(x, w*s), with
//      demod baked in: Bn = bf16(w * s[n,ic] * d[n,oc]). Kills the
//      scale->transpose dep that forced two prep kernels: ONE prep kernel
//      (transpose is unmodulated; wmod blocks self-compute scale via
//      coalesced wave-dots + demod directly from w), and k_conv needs NO
//      demod epilogue (R11's -12us epilogue mistake removed). Needs +18.9 MB
//      workspace for per-n weights -> HOST-SIDE HEDGE on ws_size: Path A
//      (2 kernels) if ws fits, else Path B = byte-exact R8 (proven 188.7).

#define NB  16
#define IC  256
#define OC  256
#define HW  64
#define HWP 66
#define SD  512
#define SPATIAL 4096
#define HWPIC 16896   // HWP*IC
#define WT2N_STRIDE 589824   // 9*256*256 elements per n

typedef __hip_bfloat16 bf16;
typedef __bf16 bf16x8 __attribute__((ext_vector_type(8)));
typedef float  f32x4  __attribute__((ext_vector_type(4)));
typedef uint32_t u32a3 __attribute__((address_space(3)));
typedef const uint32_t u32a1 __attribute__((address_space(1)));

static __device__ __forceinline__ unsigned short f2bu(float f) {
    bf16 h = __float2bfloat16(f);
    union { bf16 b; unsigned short u; } c; c.b = h; return c.u;
}
static __device__ __forceinline__ void gll16(const void* g, void* l) {
    __builtin_amdgcn_global_load_lds((u32a1*)g, (u32a3*)l, 16, 0, 0);
}

// ===================== Path A: single prep kernel ===========================
// 1808 blocks x 256 thr, all sections independent:
// [0,256):    wmod blocks (n=b>>4, oc-chunk=(b&15)*16): in-block scale via
//             wave-dots; demod from w directly; write wt2n = bf16(w*s*d).
// [256,1280): transpose blocks: x -> xs bf16 UNMODULATED (no deps).
// [1280,1808): zero 1-px border ring of padded NHWC xs.
__global__ __launch_bounds__(256)
void k_prepA(const float* __restrict__ x, const float* __restrict__ style,
             const float* __restrict__ weight, const float* __restrict__ mod_w,
             const float* __restrict__ mod_b,
             bf16* __restrict__ wt2n, bf16* __restrict__ xs) {
    __shared__ unsigned short tile[HW * 256];   // 32 KB (transpose)
    int b = blockIdx.x, t = threadIdx.x;
    if (b < 256) {
        float* scL = (float*)tile;              // 1 KB overlay
        float* red = scL + 256;                 // 1 KB
        float* dm  = red + 256;                 // 64 B
        int n = b >> 4, ocb = (b & 15) << 4;
        int l = t & 63, wv = t >> 6;
        // scale[ic] = 1 + style[n,:].mod_w[ic,:] + mod_b[ic]; wave wv owns
        // ic in [wv*64, wv*64+64); one coalesced wave-dot per ic, ILP-4.
        const float4* st4 = (const float4*)style + (size_t)n * 128 + (l << 1);
        float4 s0 = st4[0], s1 = st4[1];
        for (int g = 0; g < 64; g += 4) {
            float av[4];
            #pragma unroll
            for (int k = 0; k < 4; ++k) {
                int ic = (wv << 6) + g + k;
                const float4* mw4 = (const float4*)mod_w + (size_t)ic * 128 + (l << 1);
                float4 a0 = mw4[0], a1 = mw4[1];
                av[k] = a0.x*s0.x + a0.y*s0.y + a0.z*s0.z + a0.w*s0.w
                      + a1.x*s1.x + a1.y*s1.y + a1.z*s1.z + a1.w*s1.w;
            }
            #pragma unroll
            for (int k = 0; k < 4; ++k) {
                float a = av[k];
                #pragma unroll
                for (int off = 32; off > 0; off >>= 1) a += __shfl_down(a, off);
                if (l == 0) {
                    int ic = (wv << 6) + g + k;
                    scL[ic] = a + mod_b[ic] + 1.0f;
                }
            }
        }
        __syncthreads();
        // demod: thread (ocl=t>>4, icg=t&15); oc=ocb+ocl; ic = i*16+icg
        int ocl = t >> 4, icg = t & 15;
        int oc = ocb + ocl;
        float accd = 0.f;
        for (int i = 0; i < 16; ++i) {
            int ic = (i << 4) + icg;
            const float* wp = weight + ((size_t)oc * 256 + ic) * 9;
            float s = scL[ic];
            float sw = 0.f;
            #pragma unroll
            for (int r = 0; r < 9; ++r) { float v = wp[r]; sw += v * v; }
            accd += sw * s * s;
        }
        red[t] = accd;
        __syncthreads();
        if (t < 16) {
            float a = 0.f;
            #pragma unroll
            for (int j = 0; j < 16; ++j) a += red[(t << 4) + j];
            dm[t] = rsqrtf(a + 1e-8f);
        }
        __syncthreads();
        // write wt2n[n][r][oc][ic]: per r, thread covers ic in [icg*16,+16)
        // -> lanes 0-15 contiguous 512B per oc-group. 32B/thread/r.
        float dmo = dm[ocl];
        const float* wrow = weight + (size_t)oc * 2304;     // [ic][r]
        bf16* dst = wt2n + (size_t)n * WT2N_STRIDE + (size_t)oc * 256;
        for (int r = 0; r < 9; ++r) {
            unsigned short ob[16];
            #pragma unroll
            for (int i = 0; i < 16; ++i) {
                int ic = (icg << 4) + i;
                ob[i] = f2bu(wrow[ic * 9 + r] * scL[ic] * dmo);
            }
            uint4* d4 = (uint4*)(dst + (size_t)r * 65536 + (icg << 4));
            d4[0] = *(uint4*)&ob[0];
            d4[1] = *(uint4*)&ob[8];
        }
    } else if (b < 1280) {
        // transpose, UNMODULATED: x[n,ic,y,:] -> xs[n,y+1,x+1,ic] bf16
        int bb = b - 256, y = bb & 63, n = bb >> 6;
        const float4* xp4 = (const float4*)(x + ((size_t)n * IC) * SPATIAL + (size_t)y * HW);
        #pragma unroll
        for (int i = 0; i < 16; ++i) {
            int fid = i * 256 + t;
            int ic = fid >> 4, f4 = fid & 15;
            float4 v = xp4[(size_t)ic * 1024 + f4];
            int sp = f4 << 2;
            int sw = ic ^ ((f4 & 7) << 3);      // XOR-swizzle: <=4-way banks
            tile[(sp + 0) * 256 + sw] = f2bu(v.x);
            tile[(sp + 1) * 256 + sw] = f2bu(v.y);
            tile[(sp + 2) * 256 + sw] = f2bu(v.z);
            tile[(sp + 3) * 256 + sw] = f2bu(v.w);
        }
        __syncthreads();
        uint4* dst4 = (uint4*)(xs + (((size_t)n * HWP + (y + 1)) * HWP + 1) * IC);
        #pragma unroll
        for (int j = 0; j < 8; ++j) {
            int uid = j * 256 + t;
            int sp = uid >> 5, g = uid & 31;
            dst4[sp * 32 + g] =
                *(const uint4*)&tile[sp * 256 + ((g ^ ((sp >> 2) & 7)) << 3)];
        }
    } else {
        // zero 1-px border ring of padded NHWC xs
        uint4* xs4 = (uint4*)xs;
        int idx = b - 1280;
        int n = idx / 33, bx = idx - n * 33;
        int f = bx * 256 + t;
        int u = f >> 5, q = f & 31;
        if (u >= 260) return;
        int rb;
        if      (u <  66) rb = u;
        else if (u < 132) rb = 65 * 66 + (u - 66);
        else if (u < 196) rb = (u - 131) * 66;
        else              rb = (u - 195) * 66 + 65;
        xs4[(size_t)n * 139392 + rb * 32 + q] = make_uint4(0u, 0u, 0u, 0u);
    }
}

// ===================== Path B: R8 prep kernels (verbatim) ===================
__global__ __launch_bounds__(256)
void k_prep1(const float* __restrict__ weight, const float* __restrict__ style,
             const float* __restrict__ mod_w, const float* __restrict__ mod_b,
             float* __restrict__ wsq, bf16* __restrict__ wt2,
             uint4* __restrict__ xs4, float* __restrict__ scale) {
    int b = blockIdx.x, t = threadIdx.x;
    if (b < 256) {
        int tid = b * 256 + t;
        const float* wp = weight + (size_t)tid * 9;
        float v[9], s = 0.f;
        #pragma unroll
        for (int r = 0; r < 9; ++r) { v[r] = wp[r]; s += v[r] * v[r]; }
        wsq[tid] = s;
        #pragma unroll
        for (int r = 0; r < 9; ++r) wt2[(r << 16) + tid] = __float2bfloat16(v[r]);
    } else if (b < 784) {
        int idx = b - 256;
        int n = idx / 33, bx = idx - n * 33;
        int f = bx * 256 + t;
        int u = f >> 5, q = f & 31;
        if (u >= 260) return;
        int rb;
        if      (u <  66) rb = u;
        else if (u < 132) rb = 65 * 66 + (u - 66);
        else if (u < 196) rb = (u - 131) * 66;
        else              rb = (u - 195) * 66 + 65;
        xs4[(size_t)n * 139392 + rb * 32 + q] = make_uint4(0u, 0u, 0u, 0u);
    } else {
        int lane = t & 63;
        int w = (b - 784) * 4 + (t >> 6);
        int n = w >> 8, ic = w & 255;
        const float4* mw4 = (const float4*)mod_w + (size_t)ic * 128 + lane * 2;
        const float4* st4 = (const float4*)style + (size_t)n * 128 + lane * 2;
        float4 a0 = mw4[0], a1 = mw4[1], s0 = st4[0], s1 = st4[1];
        float acc = a0.x*s0.x + a0.y*s0.y + a0.z*s0.z + a0.w*s0.w
                  + a1.x*s1.x + a1.y*s1.y + a1.z*s1.z + a1.w*s1.w;
        #pragma unroll
        for (int off = 32; off > 0; off >>= 1) acc += __shfl_down(acc, off);
        if (lane == 0) scale[w] = acc + mod_b[ic] + 1.0f;
    }
}

__global__ __launch_bounds__(256)
void k_prep2(const float* __restrict__ x, const float* __restrict__ scale,
             const float* __restrict__ wsq, bf16* __restrict__ xs,
             float* __restrict__ demod) {
    __shared__ unsigned short tile[HW * 256];
    int b = blockIdx.x, t = threadIdx.x;
    if (b < 1024) {
        int y = b & 63, n = b >> 6;
        const float* sc = scale + n * IC;
        const float4* xp4 = (const float4*)(x + ((size_t)n * IC) * SPATIAL + (size_t)y * HW);
        #pragma unroll
        for (int i = 0; i < 16; ++i) {
            int fid = i * 256 + t;
            int ic = fid >> 4, f4 = fid & 15;
            float4 v = xp4[(size_t)ic * 1024 + f4];
            float s = sc[ic];
            int sp = f4 << 2;
            int sw = ic ^ ((f4 & 7) << 3);
            tile[(sp + 0) * 256 + sw] = f2bu(v.x * s);
            tile[(sp + 1) * 256 + sw] = f2bu(v.y * s);
            tile[(sp + 2) * 256 + sw] = f2bu(v.z * s);
            tile[(sp + 3) * 256 + sw] = f2bu(v.w * s);
        }
        __syncthreads();
        uint4* dst4 = (uint4*)(xs + (((size_t)n * HWP + (y + 1)) * HWP + 1) * IC);
        #pragma unroll
        for (int j = 0; j < 8; ++j) {
            int uid = j * 256 + t;
            int sp = uid >> 5, g = uid & 31;
            dst4[sp * 32 + g] =
                *(const uint4*)&tile[sp * 256 + ((g ^ ((sp >> 2) & 7)) << 3)];
        }
    } else {
        int n = b - 1024, oc = t;
        float* sc = (float*)tile;
        sc[t] = scale[n * IC + t];
        __syncthreads();
        const float4* wp4 = (const float4*)(wsq + (size_t)oc * IC);
        const float4* sc4 = (const float4*)sc;
        float acc = 0.f;
        #pragma unroll 8
        for (int i = 0; i < 64; ++i) {
            float4 q = wp4[i], s = sc4[i];
            acc += q.x*s.x*s.x + q.y*s.y*s.y + q.z*s.z*s.z + q.w*s.w*s.w;
        }
        demod[n * OC + oc] = rsqrtf(acc + 1e-8f);
    }
}

// ===================== k_conv (R8 core; PERN = per-n weights) ===============
#define VM4 asm volatile("s_waitcnt vmcnt(4)" ::: "memory")
#define VM2 asm volatile("s_waitcnt vmcnt(2)" ::: "memory")
#define VM0 asm volatile("s_waitcnt vmcnt(0)" ::: "memory")
#define BAR __builtin_amdgcn_s_barrier()
#define SB0 __builtin_amdgcn_sched_barrier(0)

template<int PERN>
__global__ __launch_bounds__(512, 2)
void k_conv(const bf16* __restrict__ xs, const bf16* __restrict__ wt2,
            const float* __restrict__ demod, float* __restrict__ out) {
    extern __shared__ char smem[];              // 128 KiB
    int t = threadIdx.x, l = t & 63, w = t >> 6;
    int wm = w & 1, wn = w >> 1;
    int bid = blockIdx.x;
    int work = ((bid & 7) << 5) | (bid >> 3);   // XCD-contiguous: xcd*32 + slot
    int nimg = work >> 4;
    int ybase = (work & 15) << 2;
    int spb = (work & 15) << 8;

    int srow = (w << 3) + (l >> 3);
    int gseg = (l & 7) ^ (l >> 3);
    const bf16* gA = xs + (((size_t)nimg * HWP + ybase) * HWP + srow) * IC + (gseg << 3);
    const bf16* gB = wt2 + (PERN ? (size_t)nimg * WT2N_STRIDE : (size_t)0)
                   + ((size_t)srow << 8) + (gseg << 3);
    int stW = w << 10;

    int aRow = ((wm << 6) + (l & 15)) << 7;
    int bRow = ((wn << 5) + (l & 15)) << 7;
    int sg0 = ((l >> 4) ^ (l & 7)) << 4;
    int sg1 = sg0 ^ 64;
    int ocol = l & 15;

    f32x4 acc[4][4][2];
    #pragma unroll
    for (int p = 0; p < 4; ++p)
        #pragma unroll
        for (int m = 0; m < 4; ++m)
            #pragma unroll
            for (int n = 0; n < 2; ++n) acc[p][m][n] = (f32x4){0.f, 0.f, 0.f, 0.f};

    bf16x8 afA[4][2], afB[4][2], bf0A[2][2], bf0B[2][2], bf1[2][2];

#define STG_A(ha, PARN, AOFF) do {                                          \
    const bf16* s_ = gA + (AOFF) + (ha) * 2 * HWPIC;                        \
    char* d_ = smem + (PARN) * 32768 + (ha) * 16384 + stW;                  \
    gll16(s_, d_); gll16(s_ + HWPIC, d_ + 8192); } while (0)
#define STG_B(hb, PARN, BOFF) do {                                          \
    const bf16* s_ = gB + (BOFF) + (hb) * (128 * IC);                       \
    char* d_ = smem + 65536 + (PARN) * 32768 + (hb) * 16384 + stW;          \
    gll16(s_, d_); gll16(s_ + 64 * IC, d_ + 8192); } while (0)
#define RD_A(DST, BASE) do { const char* A_ = (const char*)(BASE);          \
    _Pragma("unroll") for (int m_ = 0; m_ < 4; ++m_) {                      \
        DST[m_][0] = *(const bf16x8*)(A_ + m_ * 2048 + sg0);                \
        DST[m_][1] = *(const bf16x8*)(A_ + m_ * 2048 + sg1); } } while (0)
#define RD_B(DST, BASE) do { const char* B_ = (const char*)(BASE);          \
    _Pragma("unroll") for (int n_ = 0; n_ < 2; ++n_) {                      \
        DST[n_][0] = *(const bf16x8*)(B_ + n_ * 2048 + sg0);                \
        DST[n_][1] = *(const bf16x8*)(B_ + n_ * 2048 + sg1); } } while (0)
#define MM(P, AF, BF) do {                                                  \
    __builtin_amdgcn_s_setprio(1);                                          \
    _Pragma("unroll") for (int kk_ = 0; kk_ < 2; ++kk_)                     \
    _Pragma("unroll") for (int m_ = 0; m_ < 4; ++m_)                        \
    _Pragma("unroll") for (int n_ = 0; n_ < 2; ++n_)                        \
        acc[P][m_][n_] = __builtin_amdgcn_mfma_f32_16x16x32_bf16(           \
            AF[m_][kk_], BF[n_][kk_], acc[P][m_][n_], 0, 0, 0);             \
    __builtin_amdgcn_s_setprio(0); } while (0)

#define TILE(PAR, BF0C, BF0N, AOFF1, BOFF1) do {                            \
    const char* Ap_  = smem + (PAR) * 32768;                                \
    const char* Bp_  = smem + 65536 + (PAR) * 32768;                        \
    const char* Apn_ = smem + ((PAR) ^ 1) * 32768;                          \
    const char* Bpn_ = smem + 65536 + ((PAR) ^ 1) * 32768;                  \
    STG_A(0, (PAR) ^ 1, AOFF1);                                             \
    VM4; BAR;                                                               \
    RD_B(bf1, Bp_ + 16384 + bRow);                                          \
    SB0;                                                                    \
    MM(0, afA, BF0C);                                                       \
    STG_B(0, (PAR) ^ 1, BOFF1);                                             \
    VM4; BAR;                                                               \
    RD_A(afB, Ap_ + 16384 + aRow);                                          \
    SB0;                                                                    \
    MM(1, afA, bf1);                                                        \
    STG_B(1, (PAR) ^ 1, BOFF1);                                             \
    BAR;                                                                    \
    MM(2, afB, bf1);                                                        \
    STG_A(1, (PAR) ^ 1, AOFF1);                                             \
    VM4; BAR;                                                               \
    RD_A(afA, Apn_ + aRow);                                                 \
    RD_B(BF0N, Bpn_ + bRow);                                                \
    SB0;                                                                    \
    MM(3, afB, BF0C);                                                       \
} while (0)

    STG_A(0, 0, 0);
    STG_B(0, 0, 0);
    STG_B(1, 0, 0);
    STG_A(1, 0, 0);
    VM4;
    BAR;
    RD_A(afA, smem + aRow);
    RD_B(bf0A, smem + 65536 + bRow);

    #pragma clang loop unroll(disable)
    for (int TT = 0; TT < 17; ++TT) {
        int Tn1 = 2 * TT + 1, Tn2 = 2 * TT + 2;
        int r1 = Tn1 >> 2, ic1 = (Tn1 & 3) << 6;
        int ky1 = r1 / 3, kx1 = r1 - ky1 * 3;
        int aoff1 = (ky1 * HWP + kx1) * IC + ic1, boff1 = (r1 << 16) + ic1;
        int r2 = Tn2 >> 2, ic2 = (Tn2 & 3) << 6;
        int ky2 = r2 / 3, kx2 = r2 - ky2 * 3;
        int aoff2 = (ky2 * HWP + kx2) * IC + ic2, boff2 = (r2 << 16) + ic2;
        TILE(0, bf0A, bf0B, aoff1, boff1);
        TILE(1, bf0B, bf0A, aoff2, boff2);
    }
    {   // tile 34 (par 0): stages tile 35 (r=8, ic=192)
        int aoff35 = (2 * HWP + 2) * IC + 192, boff35 = (8 << 16) + 192;
        TILE(0, bf0A, bf0B, aoff35, boff35);
    }
    {   // tile 35 tail (par 1, cur bf0B): no staging; drains 2->0
        const char* Ap_ = smem + 32768;
        const char* Bp_ = smem + 65536 + 32768;
        VM2; BAR;
        RD_B(bf1, Bp_ + 16384 + bRow);
        SB0;
        MM(0, afA, bf0B);
        VM0; BAR;
        RD_A(afB, Ap_ + 16384 + aRow);
        SB0;
        MM(1, afA, bf1);
        MM(2, afB, bf1);
        MM(3, afB, bf0B);
    }

    // epilogue: PERN -> demod already baked into B; else R8 table read
    float dmv[2][2];
    if (PERN) {
        dmv[0][0] = dmv[0][1] = dmv[1][0] = dmv[1][1] = 1.0f;
    } else {
        #pragma unroll
        for (int qb = 0; qb < 2; ++qb)
            #pragma unroll
            for (int nn = 0; nn < 2; ++nn)
                dmv[qb][nn] = demod[nimg * OC + (qb << 7) + (wn << 5) + (nn << 4) + ocol];
    }

    int orow = (l >> 4) << 2;
    #pragma unroll
    for (int p = 0; p < 4; ++p) {
        int qa = p >> 1, qb = qa ^ (p & 1);
        #pragma unroll
        for (int n = 0; n < 2; ++n) {
            int oc = (qb << 7) + (wn << 5) + (n << 4) + ocol;
            float d = dmv[qb][n];
            size_t ob = ((size_t)(nimg * OC + oc)) * SPATIAL
                      + spb + (qa << 7) + (wm << 6) + orow;
            #pragma unroll
            for (int m = 0; m < 4; ++m) {
                f32x4 a = acc[p][m][n];
                f32x4 o = { a[0] * d, a[1] * d, a[2] * d, a[3] * d };
                *reinterpret_cast<f32x4*>(out + ob + m * 16) = o;
            }
        }
    }
}

extern "C" void kernel_launch(void* const* d_in, const int* in_sizes, int n_in,
                              void* d_out, int out_size, void* d_ws, size_t ws_size,
                              hipStream_t stream) {
    const float* x      = (const float*)d_in[0];
    const float* style  = (const float*)d_in[1];
    const float* weight = (const float*)d_in[2];
    const float* mod_w  = (const float*)d_in[3];
    const float* mod_b  = (const float*)d_in[4];
    float* out = (float*)d_out;
    char* ws = (char*)d_ws;

    static int s_attr = 0;
    if (!s_attr) {
        auto p0 = k_conv<0>; auto p1 = k_conv<1>;
        hipFuncSetAttribute(reinterpret_cast<const void*>(p0),
                            hipFuncAttributeMaxDynamicSharedMemorySize, 131072);
        hipFuncSetAttribute(reinterpret_cast<const void*>(p1),
                            hipFuncAttributeMaxDynamicSharedMemorySize, 131072);
        s_attr = 1;
    }

    const size_t WT2N_BYTES = (size_t)NB * WT2N_STRIDE * 2;   // 18,874,368
    const size_t XS_BYTES   = (size_t)NB * HWP * HWP * IC * 2; // 35,684,352
    if (ws_size >= WT2N_BYTES + XS_BYTES) {
        // Path A: per-n modulated+demodulated weights, 2 kernels
        bf16* wt2n = (bf16*)ws;
        bf16* xs   = (bf16*)(ws + WT2N_BYTES);
        k_prepA<<<1808, 256, 0, stream>>>(x, style, weight, mod_w, mod_b,
                                          wt2n, xs);
        k_conv<1><<<256, 512, 131072, stream>>>(xs, wt2n, nullptr, out);
    } else {
        // Path B: byte-exact R8 pipeline (proven 188.7us)
        float* scale = (float*)(ws + 0);         // 16 KB
        float* demod = (float*)(ws + 16384);     // 16 KB
        float* wsq   = (float*)(ws + 32768);     // 256 KB
        bf16*  wt2   = (bf16*)(ws + 294912);     // 1.18 MB
        bf16*  xs    = (bf16*)(ws + 1474560);    // 35.7 MB
        k_prep1<<<1808, 256, 0, stream>>>(weight, style, mod_w, mod_b,
                                          wsq, wt2, (uint4*)xs, scale);
        k_prep2<<<1040, 256, 0, stream>>>(x, scale, wsq, xs, demod);
        k_conv<0><<<256, 512, 131072, stream>>>(xs, wt2, demod, out);
    }
}